// Round 9
// baseline (878.454 us; speedup 1.0000x reference)
//
#include <hip/hip_runtime.h>
#include <stdint.h>
#include <stddef.h>

#define NN 50000
#define EE 800000
#define GG 64
#define DD 64
#define HH 256

typedef float f32x4 __attribute__((ext_vector_type(4)));
typedef short s16x8 __attribute__((ext_vector_type(8)));
typedef short s16x4 __attribute__((ext_vector_type(4)));

__device__ __forceinline__ short f2bf(float f) {
    union { float f; unsigned u; } v; v.f = f;
    return (short)((v.u + 0x7FFFu + ((v.u >> 16) & 1u)) >> 16);
}

__device__ __forceinline__ s16x4 f2bf4(f32x4 v) {
    s16x4 h = { f2bf(v.x), f2bf(v.y), f2bf(v.z), f2bf(v.w) };
    return h;
}

// XOR-swizzled short index into a [64][256] bf16 tile (512B rows, 16B blocks).
// blk ^= (row&7) spreads 16-row column reads across all 8 bank groups (2 rows/group = free).
__device__ __forceinline__ int swz(int row, int s) {
    return row * 256 + ((((s >> 3) ^ (row & 7)) << 3) | (s & 7));
}

// ---------------- weight prep: fragment-contiguous bf16 layout ----------------
// Each MFMA B-fragment (wave,ct,kk) = 512 shorts (1 KB) contiguous: lane l holds
// B[k = (l>>4)*8 + kk*32 .. +8][n = <tile base> + (l&15)]. One 64-lane load = 1 KB coalesced.
__global__ void prep_weights(const float* __restrict__ eW1, const float* __restrict__ eW2,
                             const float* __restrict__ nW1, const float* __restrict__ nW2,
                             short* __restrict__ W1f, short* __restrict__ W2f,
                             short* __restrict__ NW1f, short* __restrict__ NW2f) {
    int idx = blockIdx.x * blockDim.x + threadIdx.x;   // grid covers 65536
    int lane = (idx >> 3) & 63, j = idx & 7;
    int l15 = lane & 15, lq = lane >> 4;
    {   // W1f: 128 chunks: c = (w*4+ct)*8+kk
        int c = idx >> 9;
        int n = (c >> 5) * 64 + ((c >> 3) & 3) * 16 + l15;
        int k = lq * 8 + (c & 7) * 32 + j;
        W1f[idx] = f2bf(eW1[k * 256 + n]);
    }
    if (idx < 49152) {  // NW1f: 96 chunks: c = w*24 + ct*6 + kk  (K=192)
        int c = idx >> 9;
        int w = c / 24, r = c - w * 24;
        int n = w * 64 + (r / 6) * 16 + l15;
        int k = lq * 8 + (r % 6) * 32 + j;
        NW1f[idx] = f2bf(nW1[k * 256 + n]);
    }
    if (idx < 16384) {  // W2f/NW2f: 32 chunks: c = w*8 + kk  (N=64)
        int c = idx >> 9;
        int n = (c >> 3) * 16 + l15;
        int k = lq * 8 + (c & 7) * 32 + j;
        W2f[idx]  = f2bf(eW2[k * 64 + n]);
        NW2f[idx] = f2bf(nW2[k * 64 + n]);
    }
}

#define SA1 264   // padded LDS stride for node kernel (K=256 + 8 bf16)
#define SAN 200   // padded LDS stride for node A (K=192 + 8)

// ---------------- edge kernel: ef_new = MLP([ef, nf[src], nf[dst], u[egid]]) ----------------
// r6 pipeline, LDS shrunk to exactly 32KB (XOR swizzle, indices in registers) -> 5 blocks/CU.
__global__ __launch_bounds__(256, 5) void edge_kernel(
    const float* __restrict__ nf, const float* __restrict__ ef, const float* __restrict__ u,
    const int* __restrict__ src, const int* __restrict__ dst, const int* __restrict__ egid,
    const short* __restrict__ W1f, const float* __restrict__ b1,
    const short* __restrict__ W2f, const float* __restrict__ b2,
    float* __restrict__ ef_new, float* __restrict__ agg_m, float* __restrict__ e_aggr)
{
    __shared__ __align__(16) short As[64 * 256];   // 32768 B exactly: A tile / Y1 tile / Y2+redS overlay

    const int t = threadIdx.x;
    const int e0 = blockIdx.x * 64;
    const int wave = t >> 6, lane = t & 63;
    const int l15 = lane & 15, lq = lane >> 4;

    // ---- per-wave coalesced index loads (all waves hold dst/gid in registers)
    const int dstv = dst[e0 + lane];
    const int gidv = egid[e0 + lane];
    int idxv;
    if (wave == 0)      idxv = e0 + lane;                 // ef rows: identity
    else if (wave == 1) idxv = src[e0 + lane];
    else if (wave == 2) idxv = dstv;
    else                idxv = gidv;

    const float* segbase = (wave == 0) ? ef : (wave == 3) ? u : nf;

    // ---- gather: wave w loads segment w for all 64 rows (16 lanes per row, 256B contiguous)
    {
        const int rsub = lane >> 4;        // 0..3
        const int c4 = (lane & 15) * 4;    // float offset within segment
        #pragma unroll
        for (int r = 0; r < 16; ++r) {
            const int row = r * 4 + rsub;
            const float* sp = segbase + (size_t)__shfl(idxv, row) * 64 + c4;
            f32x4 v = *(const f32x4*)sp;
            *(s16x4*)(As + swz(row, wave * 64 + c4)) = f2bf4(v);
        }
    }
    __syncthreads();   // B1: A tile ready

    // ---- phase 1: Y1[64x256] = A @ W1 ; wave w owns cols [w*64, w*64+64)
    f32x4 acc[4][4] = {};
    const short* bB = W1f + (size_t)(wave * 32) * 512 + lane * 8;   // chunk = w*32 + ct*8 + kk
    #pragma unroll
    for (int kk = 0; kk < 8; ++kk) {
        s16x8 a[4], b[4];
        #pragma unroll
        for (int rt = 0; rt < 4; ++rt) a[rt] = *(const s16x8*)(As + swz(rt * 16 + l15, lq * 8 + kk * 32));
        #pragma unroll
        for (int ct = 0; ct < 4; ++ct) b[ct] = *(const s16x8*)(bB + (ct * 8 + kk) * 512);
        #pragma unroll
        for (int rt = 0; rt < 4; ++rt)
            #pragma unroll
            for (int ct = 0; ct < 4; ++ct)
                acc[rt][ct] = __builtin_amdgcn_mfma_f32_16x16x32_bf16(a[rt], b[ct], acc[rt][ct], 0, 0, 0);
    }
    __syncthreads();   // B2: all A reads done before Y1 overwrite

    // ---- W2 fragments: issue now; latency hides under Y1 writeback
    s16x8 w2f[8];
    {
        const short* bB2 = W2f + (size_t)(wave * 8) * 512 + lane * 8;   // chunk = w*8 + kk
        #pragma unroll
        for (int kk = 0; kk < 8; ++kk) w2f[kk] = *(const s16x8*)(bB2 + kk * 512);
    }

    // ---- Y1 = relu(acc + b1) -> bf16 back into As (swizzled)
    #pragma unroll
    for (int ct = 0; ct < 4; ++ct) {
        int col = wave * 64 + ct * 16 + l15;
        float bb = b1[col];
        #pragma unroll
        for (int rt = 0; rt < 4; ++rt)
            #pragma unroll
            for (int r = 0; r < 4; ++r) {
                int rr = rt * 16 + lq * 4 + r;
                float v = acc[rt][ct][r] + bb;
                As[swz(rr, col)] = f2bf(v > 0.f ? v : 0.f);
            }
    }
    __syncthreads();   // B3: Y1 ready

    // ---- phase 2: Y2[64x64] = Y1 @ W2 ; wave w owns cols [w*16, w*16+16)
    f32x4 acc2[4] = {};
    #pragma unroll
    for (int kk = 0; kk < 8; ++kk) {
        #pragma unroll
        for (int rt = 0; rt < 4; ++rt) {
            s16x8 a = *(const s16x8*)(As + swz(rt * 16 + l15, lq * 8 + kk * 32));
            acc2[rt] = __builtin_amdgcn_mfma_f32_16x16x32_bf16(a, w2f[kk], acc2[rt], 0, 0, 0);
        }
    }
    __syncthreads();   // B4: all Y1 reads done before Y2 overlay

    // ---- Y2 (+bias) into fp32 overlay
    float* Y2s = (float*)As;          // [64][65] floats (16640 B)
    {
        const int colo = wave * 16 + l15;
        const float bo = b2[colo];
        #pragma unroll
        for (int rt = 0; rt < 4; ++rt)
            #pragma unroll
            for (int r = 0; r < 4; ++r) {
                int rr = rt * 16 + lq * 4 + r;
                Y2s[rr * 65 + colo] = acc2[rt][r] + bo;
            }
    }
    __syncthreads();   // B5

    // ---- epilogue: wave w handles rows [w*16, w*16+16): 256B-contiguous store + atomics
    const int g0 = __shfl(gidv, 0);
    const bool uni = (g0 == __shfl(gidv, 63));   // sorted egid
    float* redS = (float*)As + 4224;             // overlay beyond Y2s (4160 floats)
    float ps = 0.f;
    #pragma unroll
    for (int r = 0; r < 16; ++r) {
        int row = wave * 16 + r;
        float v = Y2s[row * 65 + lane];
        __builtin_nontemporal_store(v, &ef_new[(size_t)(e0 + row) * 64 + lane]);
        atomicAdd(&agg_m[(size_t)__shfl(dstv, row) * 64 + lane], v);
        ps += v;
    }
    if (uni) redS[wave * 64 + lane] = ps;
    __syncthreads();   // B6

    if (uni) {
        if (wave == 0) {
            float s = redS[lane] + redS[64 + lane] + redS[128 + lane] + redS[192 + lane];
            atomicAdd(&e_aggr[g0 * 64 + lane], s);
        }
    } else if (t < 64) {
        // rare path: group boundary inside block (wave0 only; gidv is wave0's copy)
        float sum = 0.f; int g = g0;
        for (int rr = 0; rr < 64; ++rr) {
            int gg = __shfl(gidv, rr);
            if (gg != g) { atomicAdd(&e_aggr[g * 64 + t], sum); sum = 0.f; g = gg; }
            sum += Y2s[rr * 65 + t];
        }
        atomicAdd(&e_aggr[g * 64 + t], sum);
    }
}

// ---------------- node kernel: nf_new = MLP([agg_m, nf, u[ngid]]) ----------------
__global__ __launch_bounds__(256, 4) void node_kernel(
    const float* __restrict__ nf, const float* __restrict__ u,
    const int* __restrict__ ngid, const float* __restrict__ agg_m,
    const short* __restrict__ W1f, const float* __restrict__ b1,
    const short* __restrict__ W2f, const float* __restrict__ b2,
    float* __restrict__ nf_new, float* __restrict__ n_aggr)
{
    __shared__ __align__(16) short As[64 * SA1];
    __shared__ int gidS[64];
    __shared__ float redS[4][64];

    const int t = threadIdx.x;
    const int n0 = blockIdx.x * 64;

    if (t < 64) gidS[t] = (n0 + t < NN) ? ngid[n0 + t] : -1;
    __syncthreads();

    // ---- coalesced gather: agg_m/nf rows are contiguous streams; u is per-row gather
    #pragma unroll
    for (int itq = 0; itq < 4; ++itq) {
        int idx = itq * 256 + t;            // covers 64 rows x 16 f32x4
        int row = idx >> 4;
        int c4 = (idx & 15) * 4;
        bool valid = (n0 + row) < NN;
        f32x4 va = {0.f, 0.f, 0.f, 0.f}, vb = va, vc = va;
        if (valid) {
            int g = gidS[row];
            va = *(const f32x4*)(agg_m + (size_t)(n0 + row) * 64 + c4);
            vb = *(const f32x4*)(nf + (size_t)(n0 + row) * 64 + c4);
            vc = *(const f32x4*)(u + (size_t)g * 64 + c4);
        }
        short* arow = As + row * SAN;
        *(s16x4*)(arow + c4)        = f2bf4(va);
        *(s16x4*)(arow + 64 + c4)   = f2bf4(vb);
        *(s16x4*)(arow + 128 + c4)  = f2bf4(vc);
    }
    __syncthreads();

    const int wave = t >> 6, lane = t & 63;
    const int l15 = lane & 15, lq = lane >> 4;

    // phase 1: K=192
    f32x4 acc[4][4] = {};
    {
        const short* aB = As + l15 * SAN + lq * 8;
        const short* bB = W1f + (size_t)(wave * 24) * 512 + lane * 8;   // chunk = w*24 + ct*6 + kk
        #pragma unroll
        for (int kk = 0; kk < 6; ++kk) {
            s16x8 a[4], b[4];
            #pragma unroll
            for (int rt = 0; rt < 4; ++rt) a[rt] = *(const s16x8*)(aB + rt * 16 * SAN + kk * 32);
            #pragma unroll
            for (int ct = 0; ct < 4; ++ct) b[ct] = *(const s16x8*)(bB + (ct * 6 + kk) * 512);
            #pragma unroll
            for (int rt = 0; rt < 4; ++rt)
                #pragma unroll
                for (int ct = 0; ct < 4; ++ct)
                    acc[rt][ct] = __builtin_amdgcn_mfma_f32_16x16x32_bf16(a[rt], b[ct], acc[rt][ct], 0, 0, 0);
        }
    }
    __syncthreads();

    // W2 fragments early
    s16x8 w2f[8];
    {
        const short* bB2 = W2f + (size_t)(wave * 8) * 512 + lane * 8;
        #pragma unroll
        for (int kk = 0; kk < 8; ++kk) w2f[kk] = *(const s16x8*)(bB2 + kk * 512);
    }

    #pragma unroll
    for (int ct = 0; ct < 4; ++ct) {
        int col = wave * 64 + ct * 16 + l15;
        float bb = b1[col];
        #pragma unroll
        for (int rt = 0; rt < 4; ++rt)
            #pragma unroll
            for (int r = 0; r < 4; ++r) {
                int rr = rt * 16 + lq * 4 + r;
                float v = acc[rt][ct][r] + bb;
                As[rr * SA1 + col] = f2bf(v > 0.f ? v : 0.f);
            }
    }
    __syncthreads();

    // phase 2: K=256
    f32x4 acc2[4] = {};
    {
        const short* aB2 = As + l15 * SA1 + lq * 8;
        #pragma unroll
        for (int kk = 0; kk < 8; ++kk) {
            #pragma unroll
            for (int rt = 0; rt < 4; ++rt) {
                s16x8 a = *(const s16x8*)(aB2 + rt * 16 * SA1 + kk * 32);
                acc2[rt] = __builtin_amdgcn_mfma_f32_16x16x32_bf16(a, w2f[kk], acc2[rt], 0, 0, 0);
            }
        }
    }
    __syncthreads();

    float* Y2s = (float*)As;
    {
        const int colo = wave * 16 + l15;
        const float bo = b2[colo];
        #pragma unroll
        for (int rt = 0; rt < 4; ++rt)
            #pragma unroll
            for (int r = 0; r < 4; ++r) {
                int rr = rt * 16 + lq * 4 + r;
                float v = acc2[rt][r] + bo;
                Y2s[rr * 65 + colo] = ((n0 + rr) < NN) ? v : 0.f;
            }
    }
    __syncthreads();

    // ---- wave-parallel epilogue with uniform-gid fast path
    const bool uni = (gidS[0] == gidS[63]) && (gidS[0] >= 0);
    const int g0 = gidS[0];
    float ps = 0.f;
    #pragma unroll
    for (int r = 0; r < 16; ++r) {
        int row = wave * 16 + r;
        float v = Y2s[row * 65 + lane];
        if ((n0 + row) < NN) nf_new[(size_t)(n0 + row) * 64 + lane] = v;
        ps += v;
    }
    if (uni) redS[wave][lane] = ps;
    __syncthreads();

    if (uni) {
        if (wave == 0) {
            float s = redS[0][lane] + redS[1][lane] + redS[2][lane] + redS[3][lane];
            atomicAdd(&n_aggr[g0 * 64 + lane], s);
        }
    } else if (t < 64) {
        float sum = 0.f; int g = gidS[0];
        for (int rr = 0; rr < 64; ++rr) {
            int gg = gidS[rr];
            if (gg != g) {
                if (g >= 0) atomicAdd(&n_aggr[g * 64 + t], sum);
                sum = 0.f; g = gg;
            }
            sum += Y2s[rr * 65 + t];
        }
        if (g >= 0) atomicAdd(&n_aggr[g * 64 + t], sum);
    }
}

// ---------------- global kernel: u_new = MLP([e_aggr, n_aggr, u]) (fp32, tiny) ----------------
__global__ void global_kernel(const float* __restrict__ e_aggr, const float* __restrict__ n_aggr,
                              const float* __restrict__ u,
                              const float* __restrict__ gW1, const float* __restrict__ gb1,
                              const float* __restrict__ gW2, const float* __restrict__ gb2,
                              float* __restrict__ u_new)
{
    __shared__ float gin[192];
    __shared__ float hid[256];
    const int g = blockIdx.x, t = threadIdx.x;
    if (t < 64)       gin[t] = e_aggr[g * 64 + t];
    else if (t < 128) gin[t] = n_aggr[g * 64 + (t - 64)];
    else if (t < 192) gin[t] = u[g * 64 + (t - 128)];
    __syncthreads();
    float s = gb1[t];
    #pragma unroll 8
    for (int k = 0; k < 192; ++k) s += gin[k] * gW1[k * 256 + t];
    hid[t] = s > 0.f ? s : 0.f;
    __syncthreads();
    if (t < 64) {
        float o = gb2[t];
        #pragma unroll 8
        for (int k = 0; k < 256; ++k) o += hid[k] * gW2[k * 64 + t];
        u_new[g * 64 + t] = o;
    }
}

// ---------------- workspace layout (bytes) ----------------
#define WS_AGGM_OFF   0u
#define WS_AGGM_BYTES (NN * 64u * 4u)                 // 12,800,000
#define WS_EAGG_OFF   (WS_AGGM_OFF + WS_AGGM_BYTES)   // 12,800,000
#define WS_NAGG_OFF   (WS_EAGG_OFF + GG * 64u * 4u)   // 12,816,384
#define WS_ZERO_BYTES (WS_NAGG_OFF + GG * 64u * 4u)   // 12,832,768 (region to memset 0)
#define WS_W1T_OFF    WS_ZERO_BYTES                   // 65536 shorts
#define WS_W2T_OFF    (WS_W1T_OFF + 65536u * 2u)
#define WS_NW1T_OFF   (WS_W2T_OFF + 16384u * 2u)
#define WS_NW2T_OFF   (WS_NW1T_OFF + 49152u * 2u)     // end: 13,127,680 bytes

extern "C" void kernel_launch(void* const* d_in, const int* in_sizes, int n_in,
                              void* d_out, int out_size, void* d_ws, size_t ws_size,
                              hipStream_t stream) {
    const float* nf  = (const float*)d_in[0];
    const float* ef  = (const float*)d_in[1];
    const float* u   = (const float*)d_in[2];
    const int* src   = (const int*)d_in[3];
    const int* dst   = (const int*)d_in[4];
    const int* ngid  = (const int*)d_in[5];
    const int* egid  = (const int*)d_in[6];
    const float* eW1 = (const float*)d_in[7];
    const float* eb1 = (const float*)d_in[8];
    const float* eW2 = (const float*)d_in[9];
    const float* eb2 = (const float*)d_in[10];
    const float* nW1 = (const float*)d_in[11];
    const float* nb1 = (const float*)d_in[12];
    const float* nW2 = (const float*)d_in[13];
    const float* nb2 = (const float*)d_in[14];
    const float* gW1 = (const float*)d_in[15];
    const float* gb1 = (const float*)d_in[16];
    const float* gW2 = (const float*)d_in[17];
    const float* gb2 = (const float*)d_in[18];

    float* out    = (float*)d_out;
    float* nf_new = out;
    float* ef_new = out + (size_t)NN * DD;
    float* u_new  = out + (size_t)(NN + EE) * DD;

    char* ws = (char*)d_ws;
    float* agg_m  = (float*)(ws + WS_AGGM_OFF);
    float* e_aggr = (float*)(ws + WS_EAGG_OFF);
    float* n_aggr = (float*)(ws + WS_NAGG_OFF);
    short* W1f    = (short*)(ws + WS_W1T_OFF);
    short* W2f    = (short*)(ws + WS_W2T_OFF);
    short* NW1f   = (short*)(ws + WS_NW1T_OFF);
    short* NW2f   = (short*)(ws + WS_NW2T_OFF);

    hipMemsetAsync(d_ws, 0, WS_ZERO_BYTES, stream);
    prep_weights<<<256, 256, 0, stream>>>(eW1, eW2, nW1, nW2, W1f, W2f, NW1f, NW2f);
    edge_kernel<<<EE / 64, 256, 0, stream>>>(nf, ef, u, src, dst, egid,
                                             W1f, eb1, W2f, eb2, ef_new, agg_m, e_aggr);
    node_kernel<<<(NN + 63) / 64, 256, 0, stream>>>(nf, u, ngid, agg_m,
                                                    NW1f, nb1, NW2f, nb2, nf_new, n_aggr);
    global_kernel<<<GG, 256, 0, stream>>>(e_aggr, n_aggr, u, gW1, gb1, gW2, gb2, u_new);
}

// Round 10
// 624.312 us; speedup vs baseline: 1.4071x; 1.4071x over previous
//
#include <hip/hip_runtime.h>
#include <stdint.h>
#include <stddef.h>

#define NN 50000
#define EE 800000
#define GG 64
#define DD 64
#define HH 256

typedef float f32x4 __attribute__((ext_vector_type(4)));
typedef short s16x8 __attribute__((ext_vector_type(8)));
typedef short s16x4 __attribute__((ext_vector_type(4)));

__device__ __forceinline__ short f2bf(float f) {
    union { float f; unsigned u; } v; v.f = f;
    return (short)((v.u + 0x7FFFu + ((v.u >> 16) & 1u)) >> 16);
}

__device__ __forceinline__ s16x4 f2bf4(f32x4 v) {
    s16x4 h = { f2bf(v.x), f2bf(v.y), f2bf(v.z), f2bf(v.w) };
    return h;
}

// ---------------- weight prep: fragment-contiguous bf16 layout ----------------
// Each MFMA B-fragment = 512 shorts (1 KB) contiguous: lane l holds
// B[k = (l>>4)*8 + kk*32 .. +8][n = <16-col tile base> + (l&15)].
__global__ void prep_weights(const float* __restrict__ eW1, const float* __restrict__ eW2,
                             const float* __restrict__ nW1, const float* __restrict__ nW2,
                             short* __restrict__ W1f, short* __restrict__ W2f,
                             short* __restrict__ NW1f, short* __restrict__ NW2f) {
    int idx = blockIdx.x * blockDim.x + threadIdx.x;   // grid covers 65536
    int lane = (idx >> 3) & 63, j = idx & 7;
    int l15 = lane & 15, lq = lane >> 4;
    {   // W1f: 128 chunks: c = (w4*4+ct)*8+kk  (col tile = c>>3, 16 cols each)
        int c = idx >> 9;
        int n = (c >> 5) * 64 + ((c >> 3) & 3) * 16 + l15;
        int k = lq * 8 + (c & 7) * 32 + j;
        W1f[idx] = f2bf(eW1[k * 256 + n]);
    }
    if (idx < 49152) {  // NW1f: 96 chunks: c = w*24 + ct*6 + kk  (K=192)
        int c = idx >> 9;
        int w = c / 24, r = c - w * 24;
        int n = w * 64 + (r / 6) * 16 + l15;
        int k = lq * 8 + (r % 6) * 32 + j;
        NW1f[idx] = f2bf(nW1[k * 256 + n]);
    }
    if (idx < 16384) {  // W2f/NW2f: 32 chunks: c = cw*8 + kk  (N=64)
        int c = idx >> 9;
        int n = (c >> 3) * 16 + l15;
        int k = lq * 8 + (c & 7) * 32 + j;
        W2f[idx]  = f2bf(eW2[k * 64 + n]);
        NW2f[idx] = f2bf(nW2[k * 64 + n]);
    }
}

#define SA1 264   // padded LDS stride (K=256 + 8 bf16)
#define SAN 200   // padded LDS stride for node A (K=192 + 8)

// ---------------- edge kernel: ef_new = MLP([ef, nf[src], nf[dst], u[egid]]) ----------------
// 8-wave / 64-row tile: halves per-wave acc registers (32 AGPR) -> 6 waves/SIMD, 24 waves/CU.
__global__ __launch_bounds__(512, 6) void edge_kernel(
    const float* __restrict__ nf, const float* __restrict__ ef, const float* __restrict__ u,
    const int* __restrict__ src, const int* __restrict__ dst, const int* __restrict__ egid,
    const short* __restrict__ W1f, const float* __restrict__ b1,
    const short* __restrict__ W2f, const float* __restrict__ b2,
    float* __restrict__ ef_new, float* __restrict__ agg_m, float* __restrict__ e_aggr)
{
    __shared__ __align__(16) short As[64 * SA1];   // A tile / Y1 tile / Y2 fp32 + redS overlay
    __shared__ int dstS[64];
    __shared__ int gidS[64];

    const int t = threadIdx.x;
    const int e0 = blockIdx.x * 64;
    const int wave = t >> 6, lane = t & 63;
    const int l15 = lane & 15, lq = lane >> 4;
    const int seg = wave & 3, rh = wave >> 2;      // gather: segment, row-half

    // ---- index load: wave (seg,rh) covers rows [rh*32, rh*32+32)
    int idxv;
    {
        int ei = e0 + rh * 32 + (lane & 31);
        if (seg == 0)      idxv = ei;                      // ef rows: identity
        else if (seg == 1) idxv = src[ei];
        else if (seg == 2) { idxv = dst[ei]; if (lane < 32) dstS[rh * 32 + lane] = idxv; }
        else               { idxv = egid[ei]; if (lane < 32) gidS[rh * 32 + lane] = idxv; }
    }
    const float* segbase = (seg == 0) ? ef : (seg == 3) ? u : nf;

    // ---- gather: 32 rows x 256B per wave (16 lanes per row; 4 rows per instruction)
    {
        const int rsub = lane >> 4;        // 0..3
        const int c4 = (lane & 15) * 4;    // float offset within segment
        #pragma unroll
        for (int rr = 0; rr < 8; ++rr) {
            const int rl = rr * 4 + rsub;                   // local row 0..31
            const float* sp = segbase + (size_t)__shfl(idxv, rl) * 64 + c4;
            f32x4 v = *(const f32x4*)sp;
            *(s16x4*)(As + (rh * 32 + rl) * SA1 + seg * 64 + c4) = f2bf4(v);
        }
    }
    __syncthreads();   // B1: A tile ready

    // ---- phase 1: Y1[64x256] = A @ W1 ; wave w owns cols [w*32, w*32+32)
    f32x4 acc[4][2] = {};
    const short* aBp = As + l15 * SA1 + lq * 8;
    const short* bB = W1f + (size_t)((wave >> 1) * 32 + (wave & 1) * 16) * 512 + lane * 8;
    #pragma unroll
    for (int kk = 0; kk < 8; ++kk) {
        s16x8 a[4], b[2];
        #pragma unroll
        for (int ct = 0; ct < 2; ++ct) b[ct] = *(const s16x8*)(bB + (ct * 8 + kk) * 512);
        #pragma unroll
        for (int rt = 0; rt < 4; ++rt) a[rt] = *(const s16x8*)(aBp + rt * 16 * SA1 + kk * 32);
        #pragma unroll
        for (int rt = 0; rt < 4; ++rt)
            #pragma unroll
            for (int ct = 0; ct < 2; ++ct)
                acc[rt][ct] = __builtin_amdgcn_mfma_f32_16x16x32_bf16(a[rt], b[ct], acc[rt][ct], 0, 0, 0);
    }
    __syncthreads();   // B2: all A reads done before Y1 overwrite

    // ---- W2 fragments (wave's phase-2 col tile cw = wave&3); hides under Y1 writeback
    s16x8 w2f[8];
    {
        const short* bB2 = W2f + (size_t)((wave & 3) * 8) * 512 + lane * 8;
        #pragma unroll
        for (int kk = 0; kk < 8; ++kk) w2f[kk] = *(const s16x8*)(bB2 + kk * 512);
    }

    // ---- Y1 = relu(acc + b1) -> bf16 back into As
    #pragma unroll
    for (int ct = 0; ct < 2; ++ct) {
        int col = wave * 32 + ct * 16 + l15;
        float bb = b1[col];
        #pragma unroll
        for (int rt = 0; rt < 4; ++rt)
            #pragma unroll
            for (int r = 0; r < 4; ++r) {
                int rr = rt * 16 + lq * 4 + r;
                float v = acc[rt][ct][r] + bb;
                As[rr * SA1 + col] = f2bf(v > 0.f ? v : 0.f);
            }
    }
    __syncthreads();   // B3: Y1 ready

    // ---- phase 2: Y2[64x64] = Y1 @ W2 ; wave w: rows [(w>>2)*32, +32) x cols [(w&3)*16, +16)
    const int rh2 = wave >> 2, cw = wave & 3;
    f32x4 acc2[2] = {};
    #pragma unroll
    for (int kk = 0; kk < 8; ++kk) {
        #pragma unroll
        for (int rt = 0; rt < 2; ++rt) {
            s16x8 a = *(const s16x8*)(As + (rh2 * 32 + rt * 16 + l15) * SA1 + lq * 8 + kk * 32);
            acc2[rt] = __builtin_amdgcn_mfma_f32_16x16x32_bf16(a, w2f[kk], acc2[rt], 0, 0, 0);
        }
    }
    __syncthreads();   // B4: all Y1 reads done before Y2 overlay

    // ---- Y2 (+bias) into fp32 overlay
    float* Y2s = (float*)As;          // [64][65] floats (16640 B)
    {
        const int colo = cw * 16 + l15;
        const float bo = b2[colo];
        #pragma unroll
        for (int rt = 0; rt < 2; ++rt)
            #pragma unroll
            for (int r = 0; r < 4; ++r) {
                int rr = rh2 * 32 + rt * 16 + lq * 4 + r;
                Y2s[rr * 65 + colo] = acc2[rt][r] + bo;
            }
    }
    __syncthreads();   // B5

    // ---- epilogue: wave w handles rows [w*8, w*8+8): 256B-contiguous store + atomics
    const bool uni = (gidS[0] == gidS[63]);   // sorted egid
    const int g0 = gidS[0];
    float* redS = (float*)As + 4224;          // overlay beyond Y2s (4160 floats); 8x64 floats
    float ps = 0.f;
    #pragma unroll
    for (int r = 0; r < 8; ++r) {
        int row = wave * 8 + r;
        float v = Y2s[row * 65 + lane];
        __builtin_nontemporal_store(v, &ef_new[(size_t)(e0 + row) * 64 + lane]);
        atomicAdd(&agg_m[(size_t)dstS[row] * 64 + lane], v);
        ps += v;
    }
    if (uni) redS[wave * 64 + lane] = ps;
    __syncthreads();   // B6

    if (uni) {
        if (wave == 0) {
            float s = 0.f;
            #pragma unroll
            for (int w = 0; w < 8; ++w) s += redS[w * 64 + lane];
            atomicAdd(&e_aggr[g0 * 64 + lane], s);
        }
    } else if (t < 64) {
        // rare path: group boundary inside block
        float sum = 0.f; int g = gidS[0];
        for (int rr = 0; rr < 64; ++rr) {
            int gg = gidS[rr];
            if (gg != g) { atomicAdd(&e_aggr[g * 64 + t], sum); sum = 0.f; g = gg; }
            sum += Y2s[rr * 65 + t];
        }
        atomicAdd(&e_aggr[g * 64 + t], sum);
    }
}

// ---------------- node kernel: nf_new = MLP([agg_m, nf, u[ngid]]) (r6 version) ----------------
__global__ __launch_bounds__(256, 4) void node_kernel(
    const float* __restrict__ nf, const float* __restrict__ u,
    const int* __restrict__ ngid, const float* __restrict__ agg_m,
    const short* __restrict__ W1f, const float* __restrict__ b1,
    const short* __restrict__ W2f, const float* __restrict__ b2,
    float* __restrict__ nf_new, float* __restrict__ n_aggr)
{
    __shared__ __align__(16) short As[64 * SA1];
    __shared__ int gidS[64];
    __shared__ float redS[4][64];

    const int t = threadIdx.x;
    const int n0 = blockIdx.x * 64;

    if (t < 64) gidS[t] = (n0 + t < NN) ? ngid[n0 + t] : -1;
    __syncthreads();

    // ---- coalesced gather: agg_m/nf rows are contiguous streams; u is per-row gather
    #pragma unroll
    for (int itq = 0; itq < 4; ++itq) {
        int idx = itq * 256 + t;            // covers 64 rows x 16 f32x4
        int row = idx >> 4;
        int c4 = (idx & 15) * 4;
        bool valid = (n0 + row) < NN;
        f32x4 va = {0.f, 0.f, 0.f, 0.f}, vb = va, vc = va;
        if (valid) {
            int g = gidS[row];
            va = *(const f32x4*)(agg_m + (size_t)(n0 + row) * 64 + c4);
            vb = *(const f32x4*)(nf + (size_t)(n0 + row) * 64 + c4);
            vc = *(const f32x4*)(u + (size_t)g * 64 + c4);
        }
        short* arow = As + row * SAN;
        *(s16x4*)(arow + c4)        = f2bf4(va);
        *(s16x4*)(arow + 64 + c4)   = f2bf4(vb);
        *(s16x4*)(arow + 128 + c4)  = f2bf4(vc);
    }
    __syncthreads();

    const int wave = t >> 6, lane = t & 63;
    const int l15 = lane & 15, lq = lane >> 4;

    // phase 1: K=192
    f32x4 acc[4][4] = {};
    {
        const short* aB = As + l15 * SAN + lq * 8;
        const short* bB = W1f + (size_t)(wave * 24) * 512 + lane * 8;   // chunk = w*24 + ct*6 + kk
        #pragma unroll
        for (int kk = 0; kk < 6; ++kk) {
            s16x8 a[4], b[4];
            #pragma unroll
            for (int rt = 0; rt < 4; ++rt) a[rt] = *(const s16x8*)(aB + rt * 16 * SAN + kk * 32);
            #pragma unroll
            for (int ct = 0; ct < 4; ++ct) b[ct] = *(const s16x8*)(bB + (ct * 6 + kk) * 512);
            #pragma unroll
            for (int rt = 0; rt < 4; ++rt)
                #pragma unroll
                for (int ct = 0; ct < 4; ++ct)
                    acc[rt][ct] = __builtin_amdgcn_mfma_f32_16x16x32_bf16(a[rt], b[ct], acc[rt][ct], 0, 0, 0);
        }
    }
    __syncthreads();

    // W2 fragments early
    s16x8 w2f[8];
    {
        const short* bB2 = W2f + (size_t)(wave * 8) * 512 + lane * 8;
        #pragma unroll
        for (int kk = 0; kk < 8; ++kk) w2f[kk] = *(const s16x8*)(bB2 + kk * 512);
    }

    #pragma unroll
    for (int ct = 0; ct < 4; ++ct) {
        int col = wave * 64 + ct * 16 + l15;
        float bb = b1[col];
        #pragma unroll
        for (int rt = 0; rt < 4; ++rt)
            #pragma unroll
            for (int r = 0; r < 4; ++r) {
                int rr = rt * 16 + lq * 4 + r;
                float v = acc[rt][ct][r] + bb;
                As[rr * SA1 + col] = f2bf(v > 0.f ? v : 0.f);
            }
    }
    __syncthreads();

    // phase 2: K=256
    f32x4 acc2[4] = {};
    {
        const short* aB2 = As + l15 * SA1 + lq * 8;
        #pragma unroll
        for (int kk = 0; kk < 8; ++kk) {
            #pragma unroll
            for (int rt = 0; rt < 4; ++rt) {
                s16x8 a = *(const s16x8*)(aB2 + rt * 16 * SA1 + kk * 32);
                acc2[rt] = __builtin_amdgcn_mfma_f32_16x16x32_bf16(a, w2f[kk], acc2[rt], 0, 0, 0);
            }
        }
    }
    __syncthreads();

    float* Y2s = (float*)As;
    {
        const int colo = wave * 16 + l15;
        const float bo = b2[colo];
        #pragma unroll
        for (int rt = 0; rt < 4; ++rt)
            #pragma unroll
            for (int r = 0; r < 4; ++r) {
                int rr = rt * 16 + lq * 4 + r;
                float v = acc2[rt][r] + bo;
                Y2s[rr * 65 + colo] = ((n0 + rr) < NN) ? v : 0.f;
            }
    }
    __syncthreads();

    // ---- wave-parallel epilogue with uniform-gid fast path
    const bool uni = (gidS[0] == gidS[63]) && (gidS[0] >= 0);
    const int g0 = gidS[0];
    float ps = 0.f;
    #pragma unroll
    for (int r = 0; r < 16; ++r) {
        int row = wave * 16 + r;
        float v = Y2s[row * 65 + lane];
        if ((n0 + row) < NN) nf_new[(size_t)(n0 + row) * 64 + lane] = v;
        ps += v;
    }
    if (uni) redS[wave][lane] = ps;
    __syncthreads();

    if (uni) {
        if (wave == 0) {
            float s = redS[0][lane] + redS[1][lane] + redS[2][lane] + redS[3][lane];
            atomicAdd(&n_aggr[g0 * 64 + lane], s);
        }
    } else if (t < 64) {
        float sum = 0.f; int g = gidS[0];
        for (int rr = 0; rr < 64; ++rr) {
            int gg = gidS[rr];
            if (gg != g) {
                if (g >= 0) atomicAdd(&n_aggr[g * 64 + t], sum);
                sum = 0.f; g = gg;
            }
            sum += Y2s[rr * 65 + t];
        }
        if (g >= 0) atomicAdd(&n_aggr[g * 64 + t], sum);
    }
}

// ---------------- global kernel: u_new = MLP([e_aggr, n_aggr, u]) (fp32, tiny) ----------------
__global__ void global_kernel(const float* __restrict__ e_aggr, const float* __restrict__ n_aggr,
                              const float* __restrict__ u,
                              const float* __restrict__ gW1, const float* __restrict__ gb1,
                              const float* __restrict__ gW2, const float* __restrict__ gb2,
                              float* __restrict__ u_new)
{
    __shared__ float gin[192];
    __shared__ float hid[256];
    const int g = blockIdx.x, t = threadIdx.x;
    if (t < 64)       gin[t] = e_aggr[g * 64 + t];
    else if (t < 128) gin[t] = n_aggr[g * 64 + (t - 64)];
    else if (t < 192) gin[t] = u[g * 64 + (t - 128)];
    __syncthreads();
    float s = gb1[t];
    #pragma unroll 8
    for (int k = 0; k < 192; ++k) s += gin[k] * gW1[k * 256 + t];
    hid[t] = s > 0.f ? s : 0.f;
    __syncthreads();
    if (t < 64) {
        float o = gb2[t];
        #pragma unroll 8
        for (int k = 0; k < 256; ++k) o += hid[k] * gW2[k * 64 + t];
        u_new[g * 64 + t] = o;
    }
}

// ---------------- workspace layout (bytes) ----------------
#define WS_AGGM_OFF   0u
#define WS_AGGM_BYTES (NN * 64u * 4u)                 // 12,800,000
#define WS_EAGG_OFF   (WS_AGGM_OFF + WS_AGGM_BYTES)   // 12,800,000
#define WS_NAGG_OFF   (WS_EAGG_OFF + GG * 64u * 4u)   // 12,816,384
#define WS_ZERO_BYTES (WS_NAGG_OFF + GG * 64u * 4u)   // 12,832,768 (region to memset 0)
#define WS_W1T_OFF    WS_ZERO_BYTES                   // 65536 shorts
#define WS_W2T_OFF    (WS_W1T_OFF + 65536u * 2u)
#define WS_NW1T_OFF   (WS_W2T_OFF + 16384u * 2u)
#define WS_NW2T_OFF   (WS_NW1T_OFF + 49152u * 2u)     // end: 13,127,680 bytes

extern "C" void kernel_launch(void* const* d_in, const int* in_sizes, int n_in,
                              void* d_out, int out_size, void* d_ws, size_t ws_size,
                              hipStream_t stream) {
    const float* nf  = (const float*)d_in[0];
    const float* ef  = (const float*)d_in[1];
    const float* u   = (const float*)d_in[2];
    const int* src   = (const int*)d_in[3];
    const int* dst   = (const int*)d_in[4];
    const int* ngid  = (const int*)d_in[5];
    const int* egid  = (const int*)d_in[6];
    const float* eW1 = (const float*)d_in[7];
    const float* eb1 = (const float*)d_in[8];
    const float* eW2 = (const float*)d_in[9];
    const float* eb2 = (const float*)d_in[10];
    const float* nW1 = (const float*)d_in[11];
    const float* nb1 = (const float*)d_in[12];
    const float* nW2 = (const float*)d_in[13];
    const float* nb2 = (const float*)d_in[14];
    const float* gW1 = (const float*)d_in[15];
    const float* gb1 = (const float*)d_in[16];
    const float* gW2 = (const float*)d_in[17];
    const float* gb2 = (const float*)d_in[18];

    float* out    = (float*)d_out;
    float* nf_new = out;
    float* ef_new = out + (size_t)NN * DD;
    float* u_new  = out + (size_t)(NN + EE) * DD;

    char* ws = (char*)d_ws;
    float* agg_m  = (float*)(ws + WS_AGGM_OFF);
    float* e_aggr = (float*)(ws + WS_EAGG_OFF);
    float* n_aggr = (float*)(ws + WS_NAGG_OFF);
    short* W1f    = (short*)(ws + WS_W1T_OFF);
    short* W2f    = (short*)(ws + WS_W2T_OFF);
    short* NW1f   = (short*)(ws + WS_NW1T_OFF);
    short* NW2f   = (short*)(ws + WS_NW2T_OFF);

    hipMemsetAsync(d_ws, 0, WS_ZERO_BYTES, stream);
    prep_weights<<<256, 256, 0, stream>>>(eW1, eW2, nW1, nW2, W1f, W2f, NW1f, NW2f);
    edge_kernel<<<EE / 64, 512, 0, stream>>>(nf, ef, u, src, dst, egid,
                                             W1f, eb1, W2f, eb2, ef_new, agg_m, e_aggr);
    node_kernel<<<(NN + 63) / 64, 256, 0, stream>>>(nf, u, ngid, agg_m,
                                                    NW1f, nb1, NW2f, nb2, nf_new, n_aggr);
    global_kernel<<<GG, 256, 0, stream>>>(e_aggr, n_aggr, u, gW1, gb1, gW2, gb2, u_new);
}